// Round 8
// baseline (79.568 us; speedup 1.0000x reference)
//
#include <hip/hip_runtime.h>

// DCT2D, 8 threads per 8x8 block, single lane-transpose, 2 consecutive blocks
// per group per iteration, SOFTWARE-PIPELINED: next pair's 16 loads issue
// BEFORE current pair's compute+store (double-buffered register tiles,
// phase-unrolled x2 so all indexing is static).
//   lane r loads column r:  o[x] = X[b][x][r]
//   pass1 (local):  t[u]   = sum_x cs[x][u] * (o[x]-128)
//   -- one lane transpose --  lane r holds T[r][y]
//   pass2 (local):  res[v] = sum_y T[r][y] * cs[y][v]   -> out row r
//   coalesced 32B nontemporal row stores (keeps L3 for input; FETCH=99MB).
// cs[a][b] = c[a][b]*alpha[b]*0.5, recovered exactly from inputs:
//   c[a][b]      = dct_tensor[a,0,b,0]   (c[0][0]==1)
//   alpha[b]*0.5 = scale[b,0] * 2*sqrt(2)

typedef float vfloat4 __attribute__((ext_vector_type(4)));

__device__ __forceinline__ float uniformf(float v)
{
    return __int_as_float(__builtin_amdgcn_readfirstlane(__float_as_int(v)));
}

__device__ __forceinline__ void xpose8(float a[8], bool h1, bool h2, bool h4)
{
#pragma unroll
    for (int j = 0; j < 8; j += 2) {
        const int k = j + 1;
        float fj = __shfl_xor(a[k], 1);
        float fk = __shfl_xor(a[j], 1);
        float nj = h1 ? fj : a[j];
        float nk = h1 ? a[k] : fk;
        a[j] = nj; a[k] = nk;
    }
#pragma unroll
    for (int jj = 0; jj < 8; jj += 4) {
#pragma unroll
        for (int j0 = 0; j0 < 2; ++j0) {
            const int j = jj + j0, k = j + 2;
            float fj = __shfl_xor(a[k], 2);
            float fk = __shfl_xor(a[j], 2);
            float nj = h2 ? fj : a[j];
            float nk = h2 ? a[k] : fk;
            a[j] = nj; a[k] = nk;
        }
    }
#pragma unroll
    for (int j = 0; j < 4; ++j) {
        const int k = j + 4;
        float fj = __shfl_xor(a[k], 4);
        float fk = __shfl_xor(a[j], 4);
        float nj = h4 ? fj : a[j];
        float nk = h4 ? a[k] : fk;
        a[j] = nj; a[k] = nk;
    }
}

// 16 column loads for 2 consecutive blocks (raw, no -128 yet)
__device__ __forceinline__ void load16(float o[16], const float* __restrict__ x,
                                       int b0, int lane)
{
    const float* p = x + (size_t)b0 * 64 + lane;
#pragma unroll
    for (int xx = 0; xx < 8; ++xx) o[xx] = p[xx * 8];
#pragma unroll
    for (int xx = 0; xx < 8; ++xx) o[8 + xx] = p[64 + xx * 8];
}

// column data o[8] (already -128'd) -> output row `lane` res[8]
__device__ __forceinline__ void dct_block(const float o[8], float res[8],
                                          const float cs[8][8],
                                          bool h1, bool h2, bool h4)
{
    float t[8];
#pragma unroll
    for (int u = 0; u < 8; ++u) {
        float s = 0.0f;
#pragma unroll
        for (int xx = 0; xx < 8; ++xx) s = fmaf(o[xx], cs[xx][u], s);
        t[u] = s;
    }
    xpose8(t, h1, h2, h4);
#pragma unroll
    for (int v = 0; v < 8; ++v) {
        float s = 0.0f;
#pragma unroll
        for (int y = 0; y < 8; ++y) s = fmaf(t[y], cs[y][v], s);
        res[v] = s;
    }
}

// process a loaded 2-block tile and store it
__device__ __forceinline__ void proc2(const float o[16], float* __restrict__ out,
                                      int b0, int lane, const float cs[8][8],
                                      bool h1, bool h2, bool h4)
{
    float oA[8], oB[8];
#pragma unroll
    for (int xx = 0; xx < 8; ++xx) { oA[xx] = o[xx] - 128.0f; oB[xx] = o[8 + xx] - 128.0f; }
    float rA[8], rB[8];
    dct_block(oA, rA, cs, h1, h2, h4);
    dct_block(oB, rB, cs, h1, h2, h4);
    float* op = out + (size_t)b0 * 64 + lane * 8;
    vfloat4 sA0 = { rA[0], rA[1], rA[2], rA[3] };
    vfloat4 sA1 = { rA[4], rA[5], rA[6], rA[7] };
    vfloat4 sB0 = { rB[0], rB[1], rB[2], rB[3] };
    vfloat4 sB1 = { rB[4], rB[5], rB[6], rB[7] };
    __builtin_nontemporal_store(sA0, reinterpret_cast<vfloat4*>(op));
    __builtin_nontemporal_store(sA1, reinterpret_cast<vfloat4*>(op + 4));
    __builtin_nontemporal_store(sB0, reinterpret_cast<vfloat4*>(op + 64));
    __builtin_nontemporal_store(sB1, reinterpret_cast<vfloat4*>(op + 68));
}

__global__ __launch_bounds__(256) void dct2d_kernel(
    const float* __restrict__ x,
    const float* __restrict__ dct,     // [8,8,8,8] = c[x,u]*c[y,v]
    const float* __restrict__ scale,   // [8,8]
    float* __restrict__ out,
    int nblocks)
{
    const int tid  = blockIdx.x * blockDim.x + threadIdx.x;
    const int lane = tid & 7;
    const int g    = tid >> 3;
    const int ngroups = (gridDim.x * blockDim.x) >> 3;
    const int step = 2 * ngroups;

    // wave-uniform folded constant matrix, forced to SGPRs
    float cs[8][8];
#pragma unroll
    for (int b = 0; b < 8; ++b) {
        const float a05 = scale[b * 8] * 2.8284271247461903f;  // alpha[b]*0.5
#pragma unroll
        for (int a = 0; a < 8; ++a)
            cs[a][b] = uniformf(dct[a * 512 + b * 8] * a05);   // c[a][b]*a05
    }

    const bool h1 = (lane & 1) != 0;
    const bool h2 = (lane & 2) != 0;
    const bool h4 = (lane & 4) != 0;

    float bufA[16], bufB[16];
    int b = 2 * g;

    if (b + 1 < nblocks) {
        load16(bufA, x, b, lane);                       // prologue prefetch
        for (;;) {
            // phase 0: prefetch next into B, compute/store A
            int bn = b + step;
            bool more = (bn + 1 < nblocks);
            if (more) load16(bufB, x, bn, lane);
            proc2(bufA, out, b, lane, cs, h1, h2, h4);
            if (!more) break;
            // phase 1: prefetch next into A, compute/store B
            int bn2 = bn + step;
            bool more2 = (bn2 + 1 < nblocks);
            if (more2) load16(bufA, x, bn2, lane);
            proc2(bufB, out, bn, lane, cs, h1, h2, h4);
            if (!more2) break;
            b = bn2;
        }
    }

    // odd-nblocks tail: last single block handled by group 0 (not hit at 786432)
    if ((nblocks & 1) && g == 0) {
        int bl = nblocks - 1;
        const float* p = x + (size_t)bl * 64 + lane;
        float o[8];
#pragma unroll
        for (int xx = 0; xx < 8; ++xx) o[xx] = p[xx * 8] - 128.0f;
        float r[8];
        dct_block(o, r, cs, h1, h2, h4);
        float* op = out + (size_t)bl * 64 + lane * 8;
        vfloat4 s0 = { r[0], r[1], r[2], r[3] };
        vfloat4 s1 = { r[4], r[5], r[6], r[7] };
        __builtin_nontemporal_store(s0, reinterpret_cast<vfloat4*>(op));
        __builtin_nontemporal_store(s1, reinterpret_cast<vfloat4*>(op + 4));
    }
}

extern "C" void kernel_launch(void* const* d_in, const int* in_sizes, int n_in,
                              void* d_out, int out_size, void* d_ws, size_t ws_size,
                              hipStream_t stream)
{
    const float* x     = (const float*)d_in[0];
    const float* dct   = (const float*)d_in[1];
    const float* scale = (const float*)d_in[2];
    float* out = (float*)d_out;

    int nblocks = in_sizes[0] / 64;   // number of 8x8 tiles (262144*3)
    int block = 256;
    int grid  = 2048;                 // 65536 groups; 786432/(2*65536)=6 iters exact

    dct2d_kernel<<<grid, block, 0, stream>>>(x, dct, scale, out, nblocks);
}